// Round 5
// baseline (158.012 us; speedup 1.0000x reference)
//
#include <hip/hip_runtime.h>

using bf16x8 = __attribute__((ext_vector_type(8))) short;
using f32x4  = __attribute__((ext_vector_type(4))) float;
typedef unsigned short u16;
typedef __attribute__((ext_vector_type(8))) unsigned short u16x8;

__device__ __forceinline__ u16 f2b(float f){
  unsigned int i=__float_as_uint(f);
  return (u16)((i + 0x7FFFu + ((i>>16)&1u))>>16);
}
__device__ __forceinline__ float b2f(u16 u){
  union{unsigned int i; float f;}v; v.i=((unsigned int)u)<<16; return v.f;
}
__device__ __forceinline__ void async16(const void* g, void* l){
  __builtin_amdgcn_global_load_lds((__attribute__((address_space(1))) void*)(g),
                                   (__attribute__((address_space(3))) void*)(l), 16, 0, 0);
}
__device__ __forceinline__ float gelu_tanh(float v){
  float u = v*(0.7978845608f + 0.0356774081f*v*v);
  float e = __expf(-2.0f*fabsf(u));
  float th = (1.0f-e)/(1.0f+e);
  th = (u<0.f)? -th : th;
  return 0.5f*v*(1.0f+th);
}

// ---------- prep: fp32 weights -> bf16, transposed to [N][K] ----------
__global__ void prep_kernel(const float* __restrict__ wqkv, const float* __restrict__ wproj,
                            const float* __restrict__ wfc1, const float* __restrict__ wfc2,
                            u16* __restrict__ tqkv, u16* __restrict__ tproj,
                            u16* __restrict__ tfc1, u16* __restrict__ tfc2)
{
  int idx = blockIdx.x*256 + threadIdx.x;
  if (idx < 49152){ int n=idx>>7, k=idx&127; tqkv[idx]=f2b(wqkv[k*384+n]); }
  else if (idx < 65536){ int t=idx-49152; int n=t>>7, k=t&127; tproj[t]=f2b(wproj[k*128+n]); }
  else if (idx < 131072){ int t=idx-65536; int n=t>>7, k=t&127; tfc1[t]=f2b(wfc1[k*512+n]); }
  else if (idx < 196608){ int t=idx-131072; int n=t>>9, k=t&511; tfc2[t]=f2b(wfc2[k*128+n]); }
}

// ---------- K2: LN1 + QKV GEMM (64-token tile, N-loop over q/k/v) ----------
// LDS layout: chunk-column-major: 16B chunk (row, c) at index c*ROWS + row
__global__ __launch_bounds__(256)
void qkv_ln_kernel(const float* __restrict__ x,
                   const float* __restrict__ ln1w, const float* __restrict__ ln1b,
                   const u16* __restrict__ tqkv, const float* __restrict__ bqkv,
                   u16* __restrict__ qb, u16* __restrict__ kb, u16* __restrict__ vb)
{
  __shared__ __align__(16) char smem[49152];
  char* lA = smem;            // 64x128 bf16, c-major chunks (16 KB)
  char* lB = smem + 16384;    // 128x128 bf16, c-major chunks (32 KB)

  const int tid = threadIdx.x;
  const int lane = tid&63, wid = tid>>6;
  const int quad = lane>>4, lrow = lane&15;
  const int m0 = blockIdx.x*64;
  const int wm = (wid&1)*32, wn = (wid>>1)*64;

  // ---- LN1 in registers: thread = (row=tid>>2, q=tid&3), 32 channels ----
  {
    const int row = tid>>2, q = tid&3;
    float xv[32];
    const float4* xr = (const float4*)(x + (size_t)(m0+row)*128 + q*32);
    float s=0.f, sq=0.f;
    #pragma unroll
    for (int c4=0;c4<8;c4++){
      float4 t = xr[c4];
      xv[c4*4]=t.x; xv[c4*4+1]=t.y; xv[c4*4+2]=t.z; xv[c4*4+3]=t.w;
      s += t.x+t.y+t.z+t.w;
      sq += t.x*t.x+t.y*t.y+t.z*t.z+t.w*t.w;
    }
    s  += __shfl_xor(s,1);  s  += __shfl_xor(s,2);
    sq += __shfl_xor(sq,1); sq += __shfl_xor(sq,2);
    float mean = s*0.0078125f;
    float rstd = rsqrtf(sq*0.0078125f - mean*mean + 1e-5f);
    const float4* wr = (const float4*)(ln1w + q*32);
    const float4* br = (const float4*)(ln1b + q*32);
    u16 nv[32];
    #pragma unroll
    for (int c4=0;c4<8;c4++){
      float4 w4 = wr[c4], b4 = br[c4];
      nv[c4*4]   = f2b((xv[c4*4]  -mean)*rstd*w4.x + b4.x);
      nv[c4*4+1] = f2b((xv[c4*4+1]-mean)*rstd*w4.y + b4.y);
      nv[c4*4+2] = f2b((xv[c4*4+2]-mean)*rstd*w4.z + b4.z);
      nv[c4*4+3] = f2b((xv[c4*4+3]-mean)*rstd*w4.w + b4.w);
    }
    #pragma unroll
    for (int cc=0;cc<4;cc++){
      u16x8 pk;
      #pragma unroll
      for (int e=0;e<8;e++) pk[e] = nv[cc*8+e];
      *(u16x8*)(lA + (((q*4+cc)*64 + row)<<4)) = pk;
    }
  }

  for (int nc=0; nc<3; nc++){
    __syncthreads();   // prev lB reads done (and lA writes visible on nc=0)
    #pragma unroll
    for (int kk=0;kk<8;kk++){
      int i = tid + kk*256;          // 2048 chunks
      int n = i&127, c = i>>7;
      async16(tqkv + (size_t)(nc*128+n)*128 + c*8, lB + i*16);
    }
    __syncthreads();

    f32x4 acc[2][4] = {};
    #pragma unroll
    for (int ks=0;ks<4;ks++){
      bf16x8 af[2], bfr[4];
      #pragma unroll
      for (int i=0;i<2;i++) af[i]  = ((const bf16x8*)lA)[(ks*4+quad)*64  + wm + i*16 + lrow];
      #pragma unroll
      for (int j=0;j<4;j++) bfr[j] = ((const bf16x8*)lB)[(ks*4+quad)*128 + wn + j*16 + lrow];
      #pragma unroll
      for (int i=0;i<2;i++)
        #pragma unroll
        for (int j=0;j<4;j++)
          acc[i][j] = __builtin_amdgcn_mfma_f32_16x16x32_bf16(af[i], bfr[j], acc[i][j], 0,0,0);
    }

    const float scale = 0.17677669529663687f;
    u16* dst = (nc==0)? qb : ((nc==1)? kb : vb);
    #pragma unroll
    for (int j=0;j<4;j++){
      int col = wn + j*16 + lrow;
      float bia = bqkv[nc*128 + col];
      #pragma unroll
      for (int i=0;i<2;i++){
        #pragma unroll
        for (int r=0;r<4;r++){
          int row = m0 + wm + i*16 + quad*4 + r;
          float val = acc[i][j][r] + bia;
          if (nc==0) val *= scale;
          dst[(size_t)row*128 + col] = f2b(val);
        }
      }
    }
  }
}

// ---------- K3: neighborhood attention (LDS halo-tiled, unchanged) ----------
__global__ __launch_bounds__(256)
void attn_kernel(const u16* __restrict__ qb, const u16* __restrict__ kb,
                 const u16* __restrict__ vb, const float* __restrict__ rpb,
                 u16* __restrict__ aout)
{
  __shared__ __align__(16) u16 kt[196*32];
  __shared__ __align__(16) u16 vt[196*32];

  const int tid = threadIdx.x;
  const int tile = blockIdx.x;
  const int bh = blockIdx.y;
  const int b = bh>>2, h = bh&3;
  const int ty = (tile/7)*8, tx = (tile%7)*8;

  #pragma unroll
  for (int k=0;k<4;k++){
    int i = tid + k*256;
    if (i < 784){
      int pos = i>>2, c = i&3;
      int ly = pos/14, lx = pos-ly*14;
      int gy = ty + ly - 3, gx = tx + lx - 3;
      float4 kv = {0,0,0,0}, vv = {0,0,0,0};
      if (gy>=0 && gy<56 && gx>=0 && gx<56){
        size_t base = ((size_t)(b*3136 + gy*56 + gx)*128 + h*32 + c*8);
        kv = *(const float4*)(kb + base);
        vv = *(const float4*)(vb + base);
      }
      ((float4*)kt)[i] = kv;
      ((float4*)vt)[i] = vv;
    }
  }
  __syncthreads();

  const int px = tid>>2, q = tid&3;
  const int ly = px>>3, lx = px&7;
  const int tok = b*3136 + (ty+ly)*56 + (tx+lx);
  const int nbase = (ly*14 + lx)*32 + q*8;

  float qv[8];
  { u16x8 qq = *(const u16x8*)(qb + (size_t)tok*128 + h*32 + q*8);
    #pragma unroll
    for (int i=0;i<8;i++) qv[i]=b2f(qq[i]); }

  float sc[49];
  #pragma unroll
  for (int ky=0;ky<7;ky++){
    #pragma unroll
    for (int kx=0;kx<7;kx++){
      int n = ky*7+kx;
      u16x8 kk = *(const u16x8*)(kt + nbase + (ky*14+kx)*32);
      float s = 0.f;
      #pragma unroll
      for (int i=0;i<8;i++) s += qv[i]*b2f(kk[i]);
      s += __shfl_xor(s,1); s += __shfl_xor(s,2);
      sc[n] = s + rpb[h*49+n];
    }
  }
  float m=-1e30f;
  #pragma unroll
  for (int n=0;n<49;n++) m = fmaxf(m, sc[n]);
  float l=0.f;
  #pragma unroll
  for (int n=0;n<49;n++){ sc[n]=__expf(sc[n]-m); l+=sc[n]; }
  float inv = 1.f/l;

  float o[8]={};
  #pragma unroll
  for (int ky=0;ky<7;ky++){
    #pragma unroll
    for (int kx=0;kx<7;kx++){
      int n = ky*7+kx;
      u16x8 vv = *(const u16x8*)(vt + nbase + (ky*14+kx)*32);
      float p = sc[n];
      #pragma unroll
      for (int i=0;i<8;i++) o[i] += p*b2f(vv[i]);
    }
  }
  u16x8 ov;
  #pragma unroll
  for (int i=0;i<8;i++) ov[i] = f2b(o[i]*inv);
  *(u16x8*)(aout + (size_t)tok*128 + h*32 + q*8) = ov;
}

// ---------- K4: PROJ + residual + LN2 + FC1 + GELU + FC2 + residual ----------
__global__ __launch_bounds__(256)
void mega_mlp_kernel(const u16* __restrict__ aout, const float* __restrict__ x,
                     const u16* __restrict__ tproj, const float* __restrict__ bproj,
                     const float* __restrict__ ln2w, const float* __restrict__ ln2b,
                     const u16* __restrict__ tfc1, const float* __restrict__ bfc1,
                     const u16* __restrict__ tfc2, const float* __restrict__ bfc2,
                     float* __restrict__ out)
{
  __shared__ __align__(16) char smem[65536];
  char* lA  = smem;            // 16 KB: aout tile -> (reused) LN red scratch -> hid chunk
  char* lB  = smem + 16384;    // 32 KB: weight chunk staging
  char* xn2 = smem + 49152;    // 16 KB: LN2 output bf16 (c-major chunks)

  const int tid = threadIdx.x;
  const int lane = tid&63, wid = tid>>6;
  const int quad = lane>>4, lrow = lane&15;
  const int m0 = blockIdx.x*64;
  const int wm = (wid&1)*32, wn = (wid>>1)*64;
  const int half = wid>>1;

  // ---- stage aout tile + tproj ----
  #pragma unroll
  for (int kk=0;kk<4;kk++){
    int i = tid + kk*256;            // 1024 chunks
    int row = i&63, c = i>>6;
    async16(aout + (size_t)(m0+row)*128 + c*8, lA + i*16);
  }
  #pragma unroll
  for (int kk=0;kk<8;kk++){
    int i = tid + kk*256;            // 2048 chunks
    int n = i&127, c = i>>7;
    async16(tproj + (size_t)n*128 + c*8, lB + i*16);
  }
  __syncthreads();

  // ---- proj MFMA ----
  f32x4 acc[2][4] = {};
  #pragma unroll
  for (int ks=0;ks<4;ks++){
    bf16x8 af[2], bfr[4];
    #pragma unroll
    for (int i=0;i<2;i++) af[i]  = ((const bf16x8*)lA)[(ks*4+quad)*64  + wm + i*16 + lrow];
    #pragma unroll
    for (int j=0;j<4;j++) bfr[j] = ((const bf16x8*)lB)[(ks*4+quad)*128 + wn + j*16 + lrow];
    #pragma unroll
    for (int i=0;i<2;i++)
      #pragma unroll
      for (int j=0;j<4;j++)
        acc[i][j] = __builtin_amdgcn_mfma_f32_16x16x32_bf16(af[i], bfr[j], acc[i][j], 0,0,0);
  }
  __syncthreads();   // lA/lB reads done; lA reusable as red scratch

  // ---- x1 = proj + bias + x (kept in registers), row-stats partials ----
  float x1v[2][4][4];
  float ps[2][4] = {}, pq[2][4] = {};
  #pragma unroll
  for (int j=0;j<4;j++){
    int col = wn + j*16 + lrow;
    float bia = bproj[col];
    #pragma unroll
    for (int i=0;i<2;i++){
      #pragma unroll
      for (int r=0;r<4;r++){
        int row = m0 + wm + i*16 + quad*4 + r;
        float val = acc[i][j][r] + bia + x[(size_t)row*128 + col];
        x1v[i][j][r] = val;
        ps[i][r] += val; pq[i][r] += val*val;
      }
    }
  }
  #pragma unroll
  for (int i=0;i<2;i++)
    #pragma unroll
    for (int r=0;r<4;r++){
      #pragma unroll
      for (int off=1; off<16; off<<=1){
        ps[i][r] += __shfl_xor(ps[i][r], off);
        pq[i][r] += __shfl_xor(pq[i][r], off);
      }
    }
  float* redS = (float*)lA;        // [half*64 + row], 128 floats
  float* redQ = redS + 128;
  if (lrow==0){
    #pragma unroll
    for (int i=0;i<2;i++)
      #pragma unroll
      for (int r=0;r<4;r++){
        int row = wm + i*16 + quad*4 + r;
        redS[half*64 + row] = ps[i][r];
        redQ[half*64 + row] = pq[i][r];
      }
  }
  __syncthreads();

  // ---- LN2 -> xn2 (bf16, c-major chunks) ----
  {
    float w2[4], b2[4];
    #pragma unroll
    for (int j=0;j<4;j++){ int col = wn+j*16+lrow; w2[j]=ln2w[col]; b2[j]=ln2b[col]; }
    #pragma unroll
    for (int i=0;i<2;i++){
      #pragma unroll
      for (int r=0;r<4;r++){
        int row = wm + i*16 + quad*4 + r;
        float mean = (redS[row] + redS[64+row])*0.0078125f;
        float var  = (redQ[row] + redQ[64+row])*0.0078125f - mean*mean;
        float rstd = rsqrtf(var + 1e-5f);
        #pragma unroll
        for (int j=0;j<4;j++){
          int col = wn + j*16 + lrow;
          u16 hv = f2b((x1v[i][j][r]-mean)*rstd*w2[j] + b2[j]);
          ((u16*)xn2)[((col>>3)*64 + row)*8 + (col&7)] = hv;
        }
      }
    }
  }
  __syncthreads();   // xn2 ready, red dead (lA free for hid chunks)

  // ---- FC1(chunk) + GELU + FC2(chunk) accumulate ----
  f32x4 acc3[2][4] = {};
  for (int nc=0; nc<4; nc++){
    if (nc>0) __syncthreads();    // prev fc2 reads of lA/lB done
    #pragma unroll
    for (int kk=0;kk<8;kk++){
      int i = tid + kk*256;
      int n = i&127, c = i>>7;
      async16(tfc1 + (size_t)(nc*128+n)*128 + c*8, lB + i*16);
    }
    __syncthreads();

    f32x4 acc2[2][4] = {};
    #pragma unroll
    for (int ks=0;ks<4;ks++){
      bf16x8 af[2], bfr[4];
      #pragma unroll
      for (int i=0;i<2;i++) af[i]  = ((const bf16x8*)xn2)[(ks*4+quad)*64  + wm + i*16 + lrow];
      #pragma unroll
      for (int j=0;j<4;j++) bfr[j] = ((const bf16x8*)lB)[(ks*4+quad)*128 + wn + j*16 + lrow];
      #pragma unroll
      for (int i=0;i<2;i++)
        #pragma unroll
        for (int j=0;j<4;j++)
          acc2[i][j] = __builtin_amdgcn_mfma_f32_16x16x32_bf16(af[i], bfr[j], acc2[i][j], 0,0,0);
    }
    // gelu -> hid chunk into lA (c-major over local col 0..127)
    #pragma unroll
    for (int j=0;j<4;j++){
      int col = wn + j*16 + lrow;
      float bia = bfc1[nc*128 + col];
      #pragma unroll
      for (int i=0;i<2;i++){
        #pragma unroll
        for (int r=0;r<4;r++){
          int row = wm + i*16 + quad*4 + r;
          float g = gelu_tanh(acc2[i][j][r] + bia);
          ((u16*)lA)[((col>>3)*64 + row)*8 + (col&7)] = f2b(g);
        }
      }
    }
    __syncthreads();   // hid chunk written, fc1 lB reads done
    #pragma unroll
    for (int kk=0;kk<8;kk++){
      int i = tid + kk*256;
      int n = i&127, c = i>>7;
      async16(tfc2 + (size_t)n*512 + nc*128 + c*8, lB + i*16);
    }
    __syncthreads();

    #pragma unroll
    for (int ks=0;ks<4;ks++){
      bf16x8 af[2], bfr[4];
      #pragma unroll
      for (int i=0;i<2;i++) af[i]  = ((const bf16x8*)lA)[(ks*4+quad)*64  + wm + i*16 + lrow];
      #pragma unroll
      for (int j=0;j<4;j++) bfr[j] = ((const bf16x8*)lB)[(ks*4+quad)*128 + wn + j*16 + lrow];
      #pragma unroll
      for (int i=0;i<2;i++)
        #pragma unroll
        for (int j=0;j<4;j++)
          acc3[i][j] = __builtin_amdgcn_mfma_f32_16x16x32_bf16(af[i], bfr[j], acc3[i][j], 0,0,0);
    }
  }

  // ---- epilogue: out = fc2 + bias + x1 (registers) ----
  #pragma unroll
  for (int j=0;j<4;j++){
    int col = wn + j*16 + lrow;
    float bia = bfc2[col];
    #pragma unroll
    for (int i=0;i<2;i++){
      #pragma unroll
      for (int r=0;r<4;r++){
        int row = m0 + wm + i*16 + quad*4 + r;
        out[(size_t)row*128 + col] = acc3[i][j][r] + bia + x1v[i][j][r];
      }
    }
  }
}

extern "C" void kernel_launch(void* const* d_in, const int* in_sizes, int n_in,
                              void* d_out, int out_size, void* d_ws, size_t ws_size,
                              hipStream_t stream)
{
  const float* x     =(const float*)d_in[0];
  const float* ln1w  =(const float*)d_in[1];
  const float* ln1b  =(const float*)d_in[2];
  const float* wqkv  =(const float*)d_in[3];
  const float* bqkv  =(const float*)d_in[4];
  const float* rpb   =(const float*)d_in[5];
  const float* wproj =(const float*)d_in[6];
  const float* bproj =(const float*)d_in[7];
  const float* ln2w  =(const float*)d_in[8];
  const float* ln2b  =(const float*)d_in[9];
  const float* wfc1  =(const float*)d_in[10];
  const float* bfc1  =(const float*)d_in[11];
  const float* wfc2  =(const float*)d_in[12];
  const float* bfc2  =(const float*)d_in[13];

  char* ws=(char*)d_ws;
  size_t o=0;
  u16* tqkv =(u16*)(ws+o); o+=98304;
  u16* tproj=(u16*)(ws+o); o+=32768;
  u16* tfc1 =(u16*)(ws+o); o+=131072;
  u16* tfc2 =(u16*)(ws+o); o+=131072;
  u16* aout =(u16*)(ws+o); o+=3211264;   // attn out bf16 [tok][128]
  u16* qb   =(u16*)(ws+o); o+=3211264;   // q scaled bf16 [tok][128]
  u16* kb   =(u16*)(ws+o); o+=3211264;
  u16* vb   =(u16*)(ws+o); o+=3211264;

  prep_kernel<<<768,256,0,stream>>>(wqkv,wproj,wfc1,wfc2,tqkv,tproj,tfc1,tfc2);
  qkv_ln_kernel<<<196,256,0,stream>>>(x,ln1w,ln1b,tqkv,bqkv,qb,kb,vb);
  attn_kernel<<<dim3(49,16),256,0,stream>>>(qb,kb,vb,rpb,aout);
  mega_mlp_kernel<<<196,256,0,stream>>>(aout,x,tproj,bproj,ln2w,ln2b,
                                        tfc1,bfc1,tfc2,bfc2,(float*)d_out);
}

// Round 6
// 142.327 us; speedup vs baseline: 1.1102x; 1.1102x over previous
//
#include <hip/hip_runtime.h>

using bf16x8 = __attribute__((ext_vector_type(8))) short;
using f32x4  = __attribute__((ext_vector_type(4))) float;
typedef unsigned short u16;
typedef __attribute__((ext_vector_type(8))) unsigned short u16x8;
typedef __attribute__((ext_vector_type(4))) unsigned short u16x4;

__device__ __forceinline__ u16 f2b(float f){
  unsigned int i=__float_as_uint(f);
  return (u16)((i + 0x7FFFu + ((i>>16)&1u))>>16);
}
__device__ __forceinline__ float b2f(u16 u){
  union{unsigned int i; float f;}v; v.i=((unsigned int)u)<<16; return v.f;
}
__device__ __forceinline__ void async16(const void* g, void* l){
  __builtin_amdgcn_global_load_lds((__attribute__((address_space(1))) void*)(g),
                                   (__attribute__((address_space(3))) void*)(l), 16, 0, 0);
}
__device__ __forceinline__ float gelu_tanh(float v){
  float u = v*(0.7978845608f + 0.0356774081f*v*v);
  float e = __expf(-2.0f*fabsf(u));
  float th = (1.0f-e)/(1.0f+e);
  th = (u<0.f)? -th : th;
  return 0.5f*v*(1.0f+th);
}

// ---------- prep: fp32 weights -> bf16, transposed to [N][K] ----------
__global__ void prep_kernel(const float* __restrict__ wqkv, const float* __restrict__ wproj,
                            const float* __restrict__ wfc1, const float* __restrict__ wfc2,
                            u16* __restrict__ tqkv, u16* __restrict__ tproj,
                            u16* __restrict__ tfc1, u16* __restrict__ tfc2)
{
  int idx = blockIdx.x*256 + threadIdx.x;
  if (idx < 49152){ int n=idx>>7, k=idx&127; tqkv[idx]=f2b(wqkv[k*384+n]); }
  else if (idx < 65536){ int t=idx-49152; int n=t>>7, k=t&127; tproj[t]=f2b(wproj[k*128+n]); }
  else if (idx < 131072){ int t=idx-65536; int n=t>>7, k=t&127; tfc1[t]=f2b(wfc1[k*512+n]); }
  else if (idx < 196608){ int t=idx-131072; int n=t>>9, k=t&511; tfc2[t]=f2b(wfc2[k*128+n]); }
}

// ---------- K2: LN1 + QKV GEMM (64-token tile, N-loop over q/k/v) ----------
__global__ __launch_bounds__(256)
void qkv_ln_kernel(const float* __restrict__ x,
                   const float* __restrict__ ln1w, const float* __restrict__ ln1b,
                   const u16* __restrict__ tqkv, const float* __restrict__ bqkv,
                   u16* __restrict__ qb, u16* __restrict__ kb, u16* __restrict__ vb)
{
  __shared__ __align__(16) char smem[49152];
  char* lA = smem;            // 64x128 bf16, c-major chunks (16 KB)
  char* lB = smem + 16384;    // 128x128 bf16, c-major chunks (32 KB)

  const int tid = threadIdx.x;
  const int lane = tid&63, wid = tid>>6;
  const int quad = lane>>4, lrow = lane&15;
  const int m0 = blockIdx.x*64;
  const int wm = (wid&1)*32, wn = (wid>>1)*64;

  // ---- LN1 in registers: thread = (row=tid>>2, q=tid&3), 32 channels ----
  {
    const int row = tid>>2, q = tid&3;
    float xv[32];
    const float4* xr = (const float4*)(x + (size_t)(m0+row)*128 + q*32);
    float s=0.f, sq=0.f;
    #pragma unroll
    for (int c4=0;c4<8;c4++){
      float4 t = xr[c4];
      xv[c4*4]=t.x; xv[c4*4+1]=t.y; xv[c4*4+2]=t.z; xv[c4*4+3]=t.w;
      s += t.x+t.y+t.z+t.w;
      sq += t.x*t.x+t.y*t.y+t.z*t.z+t.w*t.w;
    }
    s  += __shfl_xor(s,1);  s  += __shfl_xor(s,2);
    sq += __shfl_xor(sq,1); sq += __shfl_xor(sq,2);
    float mean = s*0.0078125f;
    float rstd = rsqrtf(sq*0.0078125f - mean*mean + 1e-5f);
    const float4* wr = (const float4*)(ln1w + q*32);
    const float4* br = (const float4*)(ln1b + q*32);
    u16 nv[32];
    #pragma unroll
    for (int c4=0;c4<8;c4++){
      float4 w4 = wr[c4], b4 = br[c4];
      nv[c4*4]   = f2b((xv[c4*4]  -mean)*rstd*w4.x + b4.x);
      nv[c4*4+1] = f2b((xv[c4*4+1]-mean)*rstd*w4.y + b4.y);
      nv[c4*4+2] = f2b((xv[c4*4+2]-mean)*rstd*w4.z + b4.z);
      nv[c4*4+3] = f2b((xv[c4*4+3]-mean)*rstd*w4.w + b4.w);
    }
    #pragma unroll
    for (int cc=0;cc<4;cc++){
      u16x8 pk;
      #pragma unroll
      for (int e=0;e<8;e++) pk[e] = nv[cc*8+e];
      *(u16x8*)(lA + (((q*4+cc)*64 + row)<<4)) = pk;
    }
  }

  for (int nc=0; nc<3; nc++){
    __syncthreads();
    #pragma unroll
    for (int kk=0;kk<8;kk++){
      int i = tid + kk*256;
      int n = i&127, c = i>>7;
      async16(tqkv + (size_t)(nc*128+n)*128 + c*8, lB + i*16);
    }
    __syncthreads();

    f32x4 acc[2][4] = {};
    #pragma unroll
    for (int ks=0;ks<4;ks++){
      bf16x8 af[2], bfr[4];
      #pragma unroll
      for (int i=0;i<2;i++) af[i]  = ((const bf16x8*)lA)[(ks*4+quad)*64  + wm + i*16 + lrow];
      #pragma unroll
      for (int j=0;j<4;j++) bfr[j] = ((const bf16x8*)lB)[(ks*4+quad)*128 + wn + j*16 + lrow];
      #pragma unroll
      for (int i=0;i<2;i++)
        #pragma unroll
        for (int j=0;j<4;j++)
          acc[i][j] = __builtin_amdgcn_mfma_f32_16x16x32_bf16(af[i], bfr[j], acc[i][j], 0,0,0);
    }

    const float scale = 0.17677669529663687f;
    u16* dst = (nc==0)? qb : ((nc==1)? kb : vb);
    #pragma unroll
    for (int j=0;j<4;j++){
      int col = wn + j*16 + lrow;
      float bia = bqkv[nc*128 + col];
      #pragma unroll
      for (int i=0;i<2;i++){
        #pragma unroll
        for (int r=0;r<4;r++){
          int row = m0 + wm + i*16 + quad*4 + r;
          float val = acc[i][j][r] + bia;
          if (nc==0) val *= scale;
          dst[(size_t)row*128 + col] = f2b(val);
        }
      }
    }
  }
}

// ---------- K3: MFMA neighborhood attention ----------
// Block = 8x8 pixel tile x (b,h). Wave w owns 16 px (rows 2w,2w+1 of tile);
// its neighborhood = halo rows 2w..2w+7 x 14 cols = 112 positions.
// QK^T: 7 MFMAs; mask+rpb+softmax in C-layout regs; P->LDS; PV: 8 MFMAs.
#define KT_S 40    // kt stride (u16), 16B-mult, 2-way banks
#define VT_S 232   // vt stride (u16), ch-major
#define P_S  152   // P stride (u16), conflict-free
__global__ __launch_bounds__(256)
void attn_kernel(const u16* __restrict__ qb, const u16* __restrict__ kb,
                 const u16* __restrict__ vb, const float* __restrict__ rpb,
                 u16* __restrict__ aout)
{
  __shared__ __align__(16) char smem[50192];
  u16*  kt   = (u16*)smem;                       // [196][KT_S] pos-major K
  u16*  vt   = (u16*)(smem + 15680);             // [32][VT_S]  ch-major V (pos 196..223 zero)
  u16*  Pm   = (u16*)(smem + 30528);             // 4 waves x [16][P_S]
  float* srpb= (float*)(smem + 49984);           // 49 floats

  const int tid = threadIdx.x;
  const int tile = blockIdx.x, bh = blockIdx.y;
  const int b = bh>>2, h = bh&3;
  const int ty = (tile/7)*8, tx = (tile%7)*8;
  const int lane = tid&63, wid = tid>>6;
  const int quad = lane>>4, lrow = lane&15;

  // ---- stage K (196 pos x 4 octets) ----
  #pragma unroll
  for (int kk=0;kk<4;kk++){
    int i = tid + kk*256;
    if (i < 784){
      int pos = i>>2, oct = i&3;
      int hy = pos/14, hx = pos - hy*14;
      int gy = ty + hy - 3, gx = tx + hx - 3;
      u16x8 kv = {0,0,0,0,0,0,0,0};
      if (gy>=0 && gy<56 && gx>=0 && gx<56)
        kv = *(const u16x8*)(kb + ((size_t)(b*3136 + gy*56 + gx)*128 + h*32 + oct*8));
      *(u16x8*)(kt + pos*KT_S + oct*8) = kv;
    }
  }
  // ---- stage V transposed to ch-major, pos padded with zeros to 224 ----
  #pragma unroll
  for (int kk=0;kk<4;kk++){
    int i = tid + kk*256;
    if (i < 896){
      int pos = i>>2, oct = i&3;
      u16x8 vv = {0,0,0,0,0,0,0,0};
      if (pos < 196){
        int hy = pos/14, hx = pos - hy*14;
        int gy = ty + hy - 3, gx = tx + hx - 3;
        if (gy>=0 && gy<56 && gx>=0 && gx<56)
          vv = *(const u16x8*)(vb + ((size_t)(b*3136 + gy*56 + gx)*128 + h*32 + oct*8));
      }
      #pragma unroll
      for (int j=0;j<8;j++) vt[(oct*8+j)*VT_S + pos] = vv[j];
    }
  }
  if (tid < 49) srpb[tid] = rpb[h*49 + tid];
  __syncthreads();

  // ---- Q fragment from global: lane lrow = pixel m, quad = k-octet ----
  const int pxq = wid*16 + lrow;
  const int tokq = b*3136 + (ty + (pxq>>3))*56 + tx + (pxq&7);
  bf16x8 qf = *(const bf16x8*)(qb + (size_t)tokq*128 + h*32 + quad*8);

  // ---- scores: 7 MFMAs over the wave's 112-pos strip ----
  f32x4 sc[7];
  const f32x4 zf = {0.f,0.f,0.f,0.f};
  #pragma unroll
  for (int cg=0;cg<7;cg++){
    int pos = wid*28 + cg*16 + lrow;
    bf16x8 kf = *(const bf16x8*)(kt + pos*KT_S + quad*8);
    sc[cg] = __builtin_amdgcn_mfma_f32_16x16x32_bf16(qf, kf, zf, 0,0,0);
  }

  // ---- mask + rpb (C-layout: row m=quad*4+r, col n'=cg*16+lrow) ----
  const int lyq = quad>>1;                 // (quad*4+r)>>3, r<4
  #pragma unroll
  for (int cg=0;cg<7;cg++){
    int np = cg*16 + lrow;
    int nh = np/14, hx = np - nh*14;
    int dy = nh - lyq;
    #pragma unroll
    for (int r=0;r<4;r++){
      int lx = (quad*4+r)&7;
      int dx = hx - lx;
      bool in = ((unsigned)dy<7u) && ((unsigned)dx<7u);
      float bias = srpb[in ? (dy*7+dx) : 0];
      sc[cg][r] = in ? (sc[cg][r] + bias) : -1e30f;
    }
  }
  // ---- softmax per row (reduce over 16 lanes sharing quad) ----
  float rmax[4], lsum[4], inv[4];
  #pragma unroll
  for (int r=0;r<4;r++){
    float m = sc[0][r];
    #pragma unroll
    for (int cg=1;cg<7;cg++) m = fmaxf(m, sc[cg][r]);
    m = fmaxf(m, __shfl_xor(m,1)); m = fmaxf(m, __shfl_xor(m,2));
    m = fmaxf(m, __shfl_xor(m,4)); m = fmaxf(m, __shfl_xor(m,8));
    rmax[r] = m;
    float l = 0.f;
    #pragma unroll
    for (int cg=0;cg<7;cg++){ float p = __expf(sc[cg][r]-m); sc[cg][r]=p; l+=p; }
    l += __shfl_xor(l,1); l += __shfl_xor(l,2);
    l += __shfl_xor(l,4); l += __shfl_xor(l,8);
    lsum[r]=l; inv[r]=1.f/l;
  }

  // ---- write P (bf16, pos-minor) + zero pad cols 112..127 ----
  u16* Pw = Pm + wid*16*P_S;
  #pragma unroll
  for (int cg=0;cg<7;cg++){
    int np = cg*16 + lrow;
    #pragma unroll
    for (int r=0;r<4;r++)
      Pw[(quad*4+r)*P_S + np] = f2b(sc[cg][r]);
  }
  { int zr = lane>>2, seg = lane&3;
    u16x4 z4 = {0,0,0,0};
    *(u16x4*)(Pw + zr*P_S + 112 + seg*4) = z4; }
  __syncthreads();   // P write->read ordering (cheap, guarantees lgkmcnt)

  // ---- PV: out[16px][32ch] = P[16][128] x Vt[32][128-strip] ----
  f32x4 oacc[2] = {zf, zf};
  #pragma unroll
  for (int ks=0;ks<4;ks++){
    bf16x8 pf = *(const bf16x8*)(Pw + lrow*P_S + ks*32 + quad*8);
    #pragma unroll
    for (int cg2=0;cg2<2;cg2++){
      bf16x8 vf = *(const bf16x8*)(vt + (cg2*16+lrow)*VT_S + wid*28 + ks*32 + quad*8);
      oacc[cg2] = __builtin_amdgcn_mfma_f32_16x16x32_bf16(pf, vf, oacc[cg2], 0,0,0);
    }
  }
  // ---- epilogue: normalize by 1/l, store (row m=quad*4+r -> pixel) ----
  #pragma unroll
  for (int r=0;r<4;r++){
    int px = wid*16 + quad*4 + r;
    int tok = b*3136 + (ty + (px>>3))*56 + tx + (px&7);
    #pragma unroll
    for (int cg2=0;cg2<2;cg2++){
      int ch = cg2*16 + lrow;
      aout[(size_t)tok*128 + h*32 + ch] = f2b(oacc[cg2][r]*inv[r]);
    }
  }
}

// ---------- K4: PROJ + residual + LN2 + FC1 + GELU + FC2 + residual ----------
__global__ __launch_bounds__(256)
void mega_mlp_kernel(const u16* __restrict__ aout, const float* __restrict__ x,
                     const u16* __restrict__ tproj, const float* __restrict__ bproj,
                     const float* __restrict__ ln2w, const float* __restrict__ ln2b,
                     const u16* __restrict__ tfc1, const float* __restrict__ bfc1,
                     const u16* __restrict__ tfc2, const float* __restrict__ bfc2,
                     float* __restrict__ out)
{
  __shared__ __align__(16) char smem[65536];
  char* lA  = smem;
  char* lB  = smem + 16384;
  char* xn2 = smem + 49152;

  const int tid = threadIdx.x;
  const int lane = tid&63, wid = tid>>6;
  const int quad = lane>>4, lrow = lane&15;
  const int m0 = blockIdx.x*64;
  const int wm = (wid&1)*32, wn = (wid>>1)*64;
  const int half = wid>>1;

  #pragma unroll
  for (int kk=0;kk<4;kk++){
    int i = tid + kk*256;
    int row = i&63, c = i>>6;
    async16(aout + (size_t)(m0+row)*128 + c*8, lA + i*16);
  }
  #pragma unroll
  for (int kk=0;kk<8;kk++){
    int i = tid + kk*256;
    int n = i&127, c = i>>7;
    async16(tproj + (size_t)n*128 + c*8, lB + i*16);
  }
  __syncthreads();

  f32x4 acc[2][4] = {};
  #pragma unroll
  for (int ks=0;ks<4;ks++){
    bf16x8 af[2], bfr[4];
    #pragma unroll
    for (int i=0;i<2;i++) af[i]  = ((const bf16x8*)lA)[(ks*4+quad)*64  + wm + i*16 + lrow];
    #pragma unroll
    for (int j=0;j<4;j++) bfr[j] = ((const bf16x8*)lB)[(ks*4+quad)*128 + wn + j*16 + lrow];
    #pragma unroll
    for (int i=0;i<2;i++)
      #pragma unroll
      for (int j=0;j<4;j++)
        acc[i][j] = __builtin_amdgcn_mfma_f32_16x16x32_bf16(af[i], bfr[j], acc[i][j], 0,0,0);
  }
  __syncthreads();

  float x1v[2][4][4];
  float ps[2][4] = {}, pq[2][4] = {};
  #pragma unroll
  for (int j=0;j<4;j++){
    int col = wn + j*16 + lrow;
    float bia = bproj[col];
    #pragma unroll
    for (int i=0;i<2;i++){
      #pragma unroll
      for (int r=0;r<4;r++){
        int row = m0 + wm + i*16 + quad*4 + r;
        float val = acc[i][j][r] + bia + x[(size_t)row*128 + col];
        x1v[i][j][r] = val;
        ps[i][r] += val; pq[i][r] += val*val;
      }
    }
  }
  #pragma unroll
  for (int i=0;i<2;i++)
    #pragma unroll
    for (int r=0;r<4;r++){
      #pragma unroll
      for (int off=1; off<16; off<<=1){
        ps[i][r] += __shfl_xor(ps[i][r], off);
        pq[i][r] += __shfl_xor(pq[i][r], off);
      }
    }
  float* redS = (float*)lA;
  float* redQ = redS + 128;
  if (lrow==0){
    #pragma unroll
    for (int i=0;i<2;i++)
      #pragma unroll
      for (int r=0;r<4;r++){
        int row = wm + i*16 + quad*4 + r;
        redS[half*64 + row] = ps[i][r];
        redQ[half*64 + row] = pq[i][r];
      }
  }
  __syncthreads();

  {
    float w2[4], b2[4];
    #pragma unroll
    for (int j=0;j<4;j++){ int col = wn+j*16+lrow; w2[j]=ln2w[col]; b2[j]=ln2b[col]; }
    #pragma unroll
    for (int i=0;i<2;i++){
      #pragma unroll
      for (int r=0;r<4;r++){
        int row = wm + i*16 + quad*4 + r;
        float mean = (redS[row] + redS[64+row])*0.0078125f;
        float var  = (redQ[row] + redQ[64+row])*0.0078125f - mean*mean;
        float rstd = rsqrtf(var + 1e-5f);
        #pragma unroll
        for (int j=0;j<4;j++){
          int col = wn + j*16 + lrow;
          u16 hv = f2b((x1v[i][j][r]-mean)*rstd*w2[j] + b2[j]);
          ((u16*)xn2)[((col>>3)*64 + row)*8 + (col&7)] = hv;
        }
      }
    }
  }
  __syncthreads();

  f32x4 acc3[2][4] = {};
  for (int nc=0; nc<4; nc++){
    if (nc>0) __syncthreads();
    #pragma unroll
    for (int kk=0;kk<8;kk++){
      int i = tid + kk*256;
      int n = i&127, c = i>>7;
      async16(tfc1 + (size_t)(nc*128+n)*128 + c*8, lB + i*16);
    }
    __syncthreads();

    f32x4 acc2[2][4] = {};
    #pragma unroll
    for (int ks=0;ks<4;ks++){
      bf16x8 af[2], bfr[4];
      #pragma unroll
      for (int i=0;i<2;i++) af[i]  = ((const bf16x8*)xn2)[(ks*4+quad)*64  + wm + i*16 + lrow];
      #pragma unroll
      for (int j=0;j<4;j++) bfr[j] = ((const bf16x8*)lB)[(ks*4+quad)*128 + wn + j*16 + lrow];
      #pragma unroll
      for (int i=0;i<2;i++)
        #pragma unroll
        for (int j=0;j<4;j++)
          acc2[i][j] = __builtin_amdgcn_mfma_f32_16x16x32_bf16(af[i], bfr[j], acc2[i][j], 0,0,0);
    }
    #pragma unroll
    for (int j=0;j<4;j++){
      int col = wn + j*16 + lrow;
      float bia = bfc1[nc*128 + col];
      #pragma unroll
      for (int i=0;i<2;i++){
        #pragma unroll
        for (int r=0;r<4;r++){
          int row = wm + i*16 + quad*4 + r;
          float g = gelu_tanh(acc2[i][j][r] + bia);
          ((u16*)lA)[((col>>3)*64 + row)*8 + (col&7)] = f2b(g);
        }
      }
    }
    __syncthreads();
    #pragma unroll
    for (int kk=0;kk<8;kk++){
      int i = tid + kk*256;
      int n = i&127, c = i>>7;
      async16(tfc2 + (size_t)n*512 + nc*128 + c*8, lB + i*16);
    }
    __syncthreads();

    #pragma unroll
    for (int ks=0;ks<4;ks++){
      bf16x8 af[2], bfr[4];
      #pragma unroll
      for (int i=0;i<2;i++) af[i]  = ((const bf16x8*)lA)[(ks*4+quad)*64  + wm + i*16 + lrow];
      #pragma unroll
      for (int j=0;j<4;j++) bfr[j] = ((const bf16x8*)lB)[(ks*4+quad)*128 + wn + j*16 + lrow];
      #pragma unroll
      for (int i=0;i<2;i++)
        #pragma unroll
        for (int j=0;j<4;j++)
          acc3[i][j] = __builtin_amdgcn_mfma_f32_16x16x32_bf16(af[i], bfr[j], acc3[i][j], 0,0,0);
    }
  }

  #pragma unroll
  for (int j=0;j<4;j++){
    int col = wn + j*16 + lrow;
    float bia = bfc2[col];
    #pragma unroll
    for (int i=0;i<2;i++){
      #pragma unroll
      for (int r=0;r<4;r++){
        int row = m0 + wm + i*16 + quad*4 + r;
        out[(size_t)row*128 + col] = acc3[i][j][r] + bia + x1v[i][j][r];
      }
    }
  }
}

extern "C" void kernel_launch(void* const* d_in, const int* in_sizes, int n_in,
                              void* d_out, int out_size, void* d_ws, size_t ws_size,
                              hipStream_t stream)
{
  const float* x     =(const float*)d_in[0];
  const float* ln1w  =(const float*)d_in[1];
  const float* ln1b  =(const float*)d_in[2];
  const float* wqkv  =(const float*)d_in[3];
  const float* bqkv  =(const float*)d_in[4];
  const float* rpb   =(const float*)d_in[5];
  const float* wproj =(const float*)d_in[6];
  const float* bproj =(const float*)d_in[7];
  const float* ln2w  =(const float*)d_in[8];
  const float* ln2b  =(const float*)d_in[9];
  const float* wfc1  =(const float*)d_in[10];
  const float* bfc1  =(const float*)d_in[11];
  const float* wfc2  =(const float*)d_in[12];
  const float* bfc2  =(const float*)d_in[13];

  char* ws=(char*)d_ws;
  size_t o=0;
  u16* tqkv =(u16*)(ws+o); o+=98304;
  u16* tproj=(u16*)(ws+o); o+=32768;
  u16* tfc1 =(u16*)(ws+o); o+=131072;
  u16* tfc2 =(u16*)(ws+o); o+=131072;
  u16* aout =(u16*)(ws+o); o+=3211264;
  u16* qb   =(u16*)(ws+o); o+=3211264;
  u16* kb   =(u16*)(ws+o); o+=3211264;
  u16* vb   =(u16*)(ws+o); o+=3211264;

  prep_kernel<<<768,256,0,stream>>>(wqkv,wproj,wfc1,wfc2,tqkv,tproj,tfc1,tfc2);
  qkv_ln_kernel<<<196,256,0,stream>>>(x,ln1w,ln1b,tqkv,bqkv,qb,kb,vb);
  attn_kernel<<<dim3(49,16),256,0,stream>>>(qb,kb,vb,rpb,aout);
  mega_mlp_kernel<<<196,256,0,stream>>>(aout,x,tproj,bproj,ln2w,ln2b,
                                        tfc1,bfc1,tfc2,bfc2,(float*)d_out);
}

// Round 7
// 140.350 us; speedup vs baseline: 1.1258x; 1.0141x over previous
//
#include <hip/hip_runtime.h>

using bf16x8 = __attribute__((ext_vector_type(8))) short;
using f32x4  = __attribute__((ext_vector_type(4))) float;
typedef unsigned short u16;
typedef __attribute__((ext_vector_type(8))) unsigned short u16x8;
typedef __attribute__((ext_vector_type(4))) unsigned short u16x4;

__device__ __forceinline__ u16 f2b(float f){
  unsigned int i=__float_as_uint(f);
  return (u16)((i + 0x7FFFu + ((i>>16)&1u))>>16);
}
__device__ __forceinline__ float b2f(u16 u){
  union{unsigned int i; float f;}v; v.i=((unsigned int)u)<<16; return v.f;
}
__device__ __forceinline__ void async16(const void* g, void* l){
  __builtin_amdgcn_global_load_lds((__attribute__((address_space(1))) void*)(g),
                                   (__attribute__((address_space(3))) void*)(l), 16, 0, 0);
}
__device__ __forceinline__ float gelu_tanh(float v){
  float u = v*(0.7978845608f + 0.0356774081f*v*v);
  float e = __expf(-2.0f*fabsf(u));
  float th = (1.0f-e)/(1.0f+e);
  th = (u<0.f)? -th : th;
  return 0.5f*v*(1.0f+th);
}

// ---------- prep: fp32 weights -> bf16, transposed to [N][K] ----------
__global__ void prep_kernel(const float* __restrict__ wqkv, const float* __restrict__ wproj,
                            const float* __restrict__ wfc1, const float* __restrict__ wfc2,
                            u16* __restrict__ tqkv, u16* __restrict__ tproj,
                            u16* __restrict__ tfc1, u16* __restrict__ tfc2)
{
  int idx = blockIdx.x*256 + threadIdx.x;
  if (idx < 49152){ int n=idx>>7, k=idx&127; tqkv[idx]=f2b(wqkv[k*384+n]); }
  else if (idx < 65536){ int t=idx-49152; int n=t>>7, k=t&127; tproj[t]=f2b(wproj[k*128+n]); }
  else if (idx < 131072){ int t=idx-65536; int n=t>>7, k=t&127; tfc1[t]=f2b(wfc1[k*512+n]); }
  else if (idx < 196608){ int t=idx-131072; int n=t>>9, k=t&511; tfc2[t]=f2b(wfc2[k*128+n]); }
}

// ---------- K2: LN1 + one QKV chunk GEMM. 32-token tile, grid (392, 3) ----------
__global__ __launch_bounds__(256)
void qkv_ln_kernel(const float* __restrict__ x,
                   const float* __restrict__ ln1w, const float* __restrict__ ln1b,
                   const u16* __restrict__ tqkv, const float* __restrict__ bqkv,
                   u16* __restrict__ qb, u16* __restrict__ kb, u16* __restrict__ vb)
{
  __shared__ __align__(16) char smem[40960];
  char* lA = smem;            // 32x128 bf16 c-major chunks (8 KB)
  char* lB = smem + 8192;     // 128x128 bf16 c-major chunks (32 KB)

  const int tid = threadIdx.x;
  const int lane = tid&63, wid = tid>>6;
  const int quad = lane>>4, lrow = lane&15;
  const int m0 = blockIdx.x*32;
  const int nc = blockIdx.y;
  const int wm = (wid&1)*16, wn = (wid>>1)*64;

  // ---- stage weight chunk ----
  #pragma unroll
  for (int kk=0;kk<8;kk++){
    int i = tid + kk*256;          // 2048 chunks
    int n = i&127, c = i>>7;
    async16(tqkv + (size_t)(nc*128+n)*128 + c*8, lB + i*16);
  }

  // ---- LN1 in registers: thread = (row=tid>>3, g=tid&7), 16 channels ----
  {
    const int row = tid>>3, g = tid&7;
    float xv[16];
    const float4* xr = (const float4*)(x + (size_t)(m0+row)*128 + g*16);
    float s=0.f, sq=0.f;
    #pragma unroll
    for (int c4=0;c4<4;c4++){
      float4 t = xr[c4];
      xv[c4*4]=t.x; xv[c4*4+1]=t.y; xv[c4*4+2]=t.z; xv[c4*4+3]=t.w;
      s += t.x+t.y+t.z+t.w;
      sq += t.x*t.x+t.y*t.y+t.z*t.z+t.w*t.w;
    }
    s  += __shfl_xor(s,1);  s  += __shfl_xor(s,2);  s  += __shfl_xor(s,4);
    sq += __shfl_xor(sq,1); sq += __shfl_xor(sq,2); sq += __shfl_xor(sq,4);
    float mean = s*0.0078125f;
    float rstd = rsqrtf(sq*0.0078125f - mean*mean + 1e-5f);
    const float4* wr = (const float4*)(ln1w + g*16);
    const float4* br = (const float4*)(ln1b + g*16);
    u16 nv[16];
    #pragma unroll
    for (int c4=0;c4<4;c4++){
      float4 w4 = wr[c4], b4 = br[c4];
      nv[c4*4]   = f2b((xv[c4*4]  -mean)*rstd*w4.x + b4.x);
      nv[c4*4+1] = f2b((xv[c4*4+1]-mean)*rstd*w4.y + b4.y);
      nv[c4*4+2] = f2b((xv[c4*4+2]-mean)*rstd*w4.z + b4.z);
      nv[c4*4+3] = f2b((xv[c4*4+3]-mean)*rstd*w4.w + b4.w);
    }
    #pragma unroll
    for (int cc=0;cc<2;cc++){
      u16x8 pk;
      #pragma unroll
      for (int e=0;e<8;e++) pk[e] = nv[cc*8+e];
      *(u16x8*)(lA + (((g*2+cc)*32 + row)<<4)) = pk;
    }
  }
  __syncthreads();

  // ---- MFMA: wave = 16 rows x 64 cols ----
  f32x4 acc[4] = {};
  #pragma unroll
  for (int ks=0;ks<4;ks++){
    bf16x8 af = ((const bf16x8*)lA)[(ks*4+quad)*32 + wm + lrow];
    #pragma unroll
    for (int j=0;j<4;j++){
      bf16x8 bfr = ((const bf16x8*)lB)[(ks*4+quad)*128 + wn + j*16 + lrow];
      acc[j] = __builtin_amdgcn_mfma_f32_16x16x32_bf16(af, bfr, acc[j], 0,0,0);
    }
  }

  const float scale = 0.17677669529663687f;
  u16* dst = (nc==0)? qb : ((nc==1)? kb : vb);
  #pragma unroll
  for (int j=0;j<4;j++){
    int col = wn + j*16 + lrow;
    float bia = bqkv[nc*128 + col];
    #pragma unroll
    for (int r=0;r<4;r++){
      int row = m0 + wm + quad*4 + r;
      float val = acc[j][r] + bia;
      if (nc==0) val *= scale;
      dst[(size_t)row*128 + col] = f2b(val);
    }
  }
}

// ---------- K3: MFMA neighborhood attention (unchanged from R6) ----------
#define KT_S 40
#define VT_S 232
#define P_S  152
__global__ __launch_bounds__(256)
void attn_kernel(const u16* __restrict__ qb, const u16* __restrict__ kb,
                 const u16* __restrict__ vb, const float* __restrict__ rpb,
                 u16* __restrict__ aout)
{
  __shared__ __align__(16) char smem[50192];
  u16*  kt   = (u16*)smem;
  u16*  vt   = (u16*)(smem + 15680);
  u16*  Pm   = (u16*)(smem + 30528);
  float* srpb= (float*)(smem + 49984);

  const int tid = threadIdx.x;
  const int tile = blockIdx.x, bh = blockIdx.y;
  const int b = bh>>2, h = bh&3;
  const int ty = (tile/7)*8, tx = (tile%7)*8;
  const int lane = tid&63, wid = tid>>6;
  const int quad = lane>>4, lrow = lane&15;

  #pragma unroll
  for (int kk=0;kk<4;kk++){
    int i = tid + kk*256;
    if (i < 784){
      int pos = i>>2, oct = i&3;
      int hy = pos/14, hx = pos - hy*14;
      int gy = ty + hy - 3, gx = tx + hx - 3;
      u16x8 kv = {0,0,0,0,0,0,0,0};
      if (gy>=0 && gy<56 && gx>=0 && gx<56)
        kv = *(const u16x8*)(kb + ((size_t)(b*3136 + gy*56 + gx)*128 + h*32 + oct*8));
      *(u16x8*)(kt + pos*KT_S + oct*8) = kv;
    }
  }
  #pragma unroll
  for (int kk=0;kk<4;kk++){
    int i = tid + kk*256;
    if (i < 896){
      int pos = i>>2, oct = i&3;
      u16x8 vv = {0,0,0,0,0,0,0,0};
      if (pos < 196){
        int hy = pos/14, hx = pos - hy*14;
        int gy = ty + hy - 3, gx = tx + hx - 3;
        if (gy>=0 && gy<56 && gx>=0 && gx<56)
          vv = *(const u16x8*)(vb + ((size_t)(b*3136 + gy*56 + gx)*128 + h*32 + oct*8));
      }
      #pragma unroll
      for (int j=0;j<8;j++) vt[(oct*8+j)*VT_S + pos] = vv[j];
    }
  }
  if (tid < 49) srpb[tid] = rpb[h*49 + tid];
  __syncthreads();

  const int pxq = wid*16 + lrow;
  const int tokq = b*3136 + (ty + (pxq>>3))*56 + tx + (pxq&7);
  bf16x8 qf = *(const bf16x8*)(qb + (size_t)tokq*128 + h*32 + quad*8);

  f32x4 sc[7];
  const f32x4 zf = {0.f,0.f,0.f,0.f};
  #pragma unroll
  for (int cg=0;cg<7;cg++){
    int pos = wid*28 + cg*16 + lrow;
    bf16x8 kf = *(const bf16x8*)(kt + pos*KT_S + quad*8);
    sc[cg] = __builtin_amdgcn_mfma_f32_16x16x32_bf16(qf, kf, zf, 0,0,0);
  }

  const int lyq = quad>>1;
  #pragma unroll
  for (int cg=0;cg<7;cg++){
    int np = cg*16 + lrow;
    int nh = np/14, hx = np - nh*14;
    int dy = nh - lyq;
    #pragma unroll
    for (int r=0;r<4;r++){
      int lx = (quad*4+r)&7;
      int dx = hx - lx;
      bool in = ((unsigned)dy<7u) && ((unsigned)dx<7u);
      float bias = srpb[in ? (dy*7+dx) : 0];
      sc[cg][r] = in ? (sc[cg][r] + bias) : -1e30f;
    }
  }
  float inv[4];
  #pragma unroll
  for (int r=0;r<4;r++){
    float m = sc[0][r];
    #pragma unroll
    for (int cg=1;cg<7;cg++) m = fmaxf(m, sc[cg][r]);
    m = fmaxf(m, __shfl_xor(m,1)); m = fmaxf(m, __shfl_xor(m,2));
    m = fmaxf(m, __shfl_xor(m,4)); m = fmaxf(m, __shfl_xor(m,8));
    float l = 0.f;
    #pragma unroll
    for (int cg=0;cg<7;cg++){ float p = __expf(sc[cg][r]-m); sc[cg][r]=p; l+=p; }
    l += __shfl_xor(l,1); l += __shfl_xor(l,2);
    l += __shfl_xor(l,4); l += __shfl_xor(l,8);
    inv[r]=1.f/l;
  }

  u16* Pw = Pm + wid*16*P_S;
  #pragma unroll
  for (int cg=0;cg<7;cg++){
    int np = cg*16 + lrow;
    #pragma unroll
    for (int r=0;r<4;r++)
      Pw[(quad*4+r)*P_S + np] = f2b(sc[cg][r]);
  }
  { int zr = lane>>2, seg = lane&3;
    u16x4 z4 = {0,0,0,0};
    *(u16x4*)(Pw + zr*P_S + 112 + seg*4) = z4; }
  __syncthreads();

  f32x4 oacc[2] = {zf, zf};
  #pragma unroll
  for (int ks=0;ks<4;ks++){
    bf16x8 pf = *(const bf16x8*)(Pw + lrow*P_S + ks*32 + quad*8);
    #pragma unroll
    for (int cg2=0;cg2<2;cg2++){
      bf16x8 vf = *(const bf16x8*)(vt + (cg2*16+lrow)*VT_S + wid*28 + ks*32 + quad*8);
      oacc[cg2] = __builtin_amdgcn_mfma_f32_16x16x32_bf16(pf, vf, oacc[cg2], 0,0,0);
    }
  }
  #pragma unroll
  for (int r=0;r<4;r++){
    int px = wid*16 + quad*4 + r;
    int tok = b*3136 + (ty + (px>>3))*56 + tx + (px&7);
    #pragma unroll
    for (int cg2=0;cg2<2;cg2++){
      int ch = cg2*16 + lrow;
      aout[(size_t)tok*128 + h*32 + ch] = f2b(oacc[cg2][r]*inv[r]);
    }
  }
}

// ---------- K4: PROJ + residual + LN2 + FC1 + GELU + FC2 + residual ----------
// 32-token tile, grid 392, LDS 49.7 KB -> 3 blocks/CU capacity
__global__ __launch_bounds__(256)
void mega_mlp_kernel(const u16* __restrict__ aout, const float* __restrict__ x,
                     const u16* __restrict__ tproj, const float* __restrict__ bproj,
                     const float* __restrict__ ln2w, const float* __restrict__ ln2b,
                     const u16* __restrict__ tfc1, const float* __restrict__ bfc1,
                     const u16* __restrict__ tfc2, const float* __restrict__ bfc2,
                     float* __restrict__ out)
{
  __shared__ __align__(16) char smem[49664];
  char* lA  = smem;            // 8 KB: aout tile -> hid chunk
  char* lB  = smem + 8192;     // 32 KB: weight chunk staging
  char* xn2 = smem + 40960;    // 8 KB: LN2 output bf16 (c-major chunks)
  float* redS = (float*)(smem + 49152);  // 64 floats
  float* redQ = redS + 64;               // 64 floats

  const int tid = threadIdx.x;
  const int lane = tid&63, wid = tid>>6;
  const int quad = lane>>4, lrow = lane&15;
  const int m0 = blockIdx.x*32;
  const int wm = (wid&1)*16, wn = (wid>>1)*64;
  const int half = wid>>1;

  // ---- stage aout tile + tproj ----
  #pragma unroll
  for (int kk=0;kk<2;kk++){
    int i = tid + kk*256;            // 512 chunks
    int row = i&31, c = i>>5;
    async16(aout + (size_t)(m0+row)*128 + c*8, lA + i*16);
  }
  #pragma unroll
  for (int kk=0;kk<8;kk++){
    int i = tid + kk*256;            // 2048 chunks
    int n = i&127, c = i>>7;
    async16(tproj + (size_t)n*128 + c*8, lB + i*16);
  }
  __syncthreads();

  // ---- proj MFMA (wave = 16 rows x 64 cols) ----
  f32x4 acc[4] = {};
  #pragma unroll
  for (int ks=0;ks<4;ks++){
    bf16x8 af = ((const bf16x8*)lA)[(ks*4+quad)*32 + wm + lrow];
    #pragma unroll
    for (int j=0;j<4;j++){
      bf16x8 bfr = ((const bf16x8*)lB)[(ks*4+quad)*128 + wn + j*16 + lrow];
      acc[j] = __builtin_amdgcn_mfma_f32_16x16x32_bf16(af, bfr, acc[j], 0,0,0);
    }
  }

  // ---- x1 = proj + bias + x (registers) + row-stat partials -> redbuf ----
  float x1v[4][4];
  float ps[4] = {}, pq[4] = {};
  #pragma unroll
  for (int j=0;j<4;j++){
    int col = wn + j*16 + lrow;
    float bia = bproj[col];
    #pragma unroll
    for (int r=0;r<4;r++){
      int row = m0 + wm + quad*4 + r;
      float val = acc[j][r] + bia + x[(size_t)row*128 + col];
      x1v[j][r] = val;
      ps[r] += val; pq[r] += val*val;
    }
  }
  #pragma unroll
  for (int r=0;r<4;r++){
    #pragma unroll
    for (int off=1; off<16; off<<=1){
      ps[r] += __shfl_xor(ps[r], off);
      pq[r] += __shfl_xor(pq[r], off);
    }
  }
  if (lrow==0){
    #pragma unroll
    for (int r=0;r<4;r++){
      int row = wm + quad*4 + r;
      redS[half*32 + row] = ps[r];
      redQ[half*32 + row] = pq[r];
    }
  }
  __syncthreads();

  // ---- LN2 -> xn2 (bf16, c-major chunks) ----
  {
    float w2[4], b2[4];
    #pragma unroll
    for (int j=0;j<4;j++){ int col = wn+j*16+lrow; w2[j]=ln2w[col]; b2[j]=ln2b[col]; }
    #pragma unroll
    for (int r=0;r<4;r++){
      int row = wm + quad*4 + r;
      float mean = (redS[row] + redS[32+row])*0.0078125f;
      float var  = (redQ[row] + redQ[32+row])*0.0078125f - mean*mean;
      float rstd = rsqrtf(var + 1e-5f);
      #pragma unroll
      for (int j=0;j<4;j++){
        int col = wn + j*16 + lrow;
        u16 hv = f2b((x1v[j][r]-mean)*rstd*w2[j] + b2[j]);
        ((u16*)xn2)[((col>>3)*32 + row)*8 + (col&7)] = hv;
      }
    }
  }
  __syncthreads();

  // ---- FC1(chunk) + GELU + FC2(chunk) accumulate ----
  f32x4 acc3[4] = {};
  for (int nc=0; nc<4; nc++){
    if (nc>0) __syncthreads();
    #pragma unroll
    for (int kk=0;kk<8;kk++){
      int i = tid + kk*256;
      int n = i&127, c = i>>7;
      async16(tfc1 + (size_t)(nc*128+n)*128 + c*8, lB + i*16);
    }
    __syncthreads();

    f32x4 acc2[4] = {};
    #pragma unroll
    for (int ks=0;ks<4;ks++){
      bf16x8 af = ((const bf16x8*)xn2)[(ks*4+quad)*32 + wm + lrow];
      #pragma unroll
      for (int j=0;j<4;j++){
        bf16x8 bfr = ((const bf16x8*)lB)[(ks*4+quad)*128 + wn + j*16 + lrow];
        acc2[j] = __builtin_amdgcn_mfma_f32_16x16x32_bf16(af, bfr, acc2[j], 0,0,0);
      }
    }
    #pragma unroll
    for (int j=0;j<4;j++){
      int col = wn + j*16 + lrow;
      float bia = bfc1[nc*128 + col];
      #pragma unroll
      for (int r=0;r<4;r++){
        int row = wm + quad*4 + r;
        float g = gelu_tanh(acc2[j][r] + bia);
        ((u16*)lA)[((col>>3)*32 + row)*8 + (col&7)] = f2b(g);
      }
    }
    __syncthreads();
    #pragma unroll
    for (int kk=0;kk<8;kk++){
      int i = tid + kk*256;
      int n = i&127, c = i>>7;
      async16(tfc2 + (size_t)n*512 + nc*128 + c*8, lB + i*16);
    }
    __syncthreads();

    #pragma unroll
    for (int ks=0;ks<4;ks++){
      bf16x8 af = ((const bf16x8*)lA)[(ks*4+quad)*32 + wm + lrow];
      #pragma unroll
      for (int j=0;j<4;j++){
        bf16x8 bfr = ((const bf16x8*)lB)[(ks*4+quad)*128 + wn + j*16 + lrow];
        acc3[j] = __builtin_amdgcn_mfma_f32_16x16x32_bf16(af, bfr, acc3[j], 0,0,0);
      }
    }
  }

  // ---- epilogue: out = fc2 + bias + x1 ----
  #pragma unroll
  for (int j=0;j<4;j++){
    int col = wn + j*16 + lrow;
    float bia = bfc2[col];
    #pragma unroll
    for (int r=0;r<4;r++){
      int row = m0 + wm + quad*4 + r;
      out[(size_t)row*128 + col] = acc3[j][r] + bia + x1v[j][r];
    }
  }
}

extern "C" void kernel_launch(void* const* d_in, const int* in_sizes, int n_in,
                              void* d_out, int out_size, void* d_ws, size_t ws_size,
                              hipStream_t stream)
{
  const float* x     =(const float*)d_in[0];
  const float* ln1w  =(const float*)d_in[1];
  const float* ln1b  =(const float*)d_in[2];
  const float* wqkv  =(const float*)d_in[3];
  const float* bqkv  =(const float*)d_in[4];
  const float* rpb   =(const float*)d_in[5];
  const float* wproj =(const float*)d_in[6];
  const float* bproj =(const float*)d_in[7];
  const float* ln2w  =(const float*)d_in[8];
  const float* ln2b  =(const float*)d_in[9];
  const float* wfc1  =(const float*)d_in[10];
  const float* bfc1  =(const float*)d_in[11];
  const float* wfc2  =(const float*)d_in[12];
  const float* bfc2  =(const float*)d_in[13];

  char* ws=(char*)d_ws;
  size_t o=0;
  u16* tqkv =(u16*)(ws+o); o+=98304;
  u16* tproj=(u16*)(ws+o); o+=32768;
  u16* tfc1 =(u16*)(ws+o); o+=131072;
  u16* tfc2 =(u16*)(ws+o); o+=131072;
  u16* aout =(u16*)(ws+o); o+=3211264;
  u16* qb   =(u16*)(ws+o); o+=3211264;
  u16* kb   =(u16*)(ws+o); o+=3211264;
  u16* vb   =(u16*)(ws+o); o+=3211264;

  prep_kernel<<<768,256,0,stream>>>(wqkv,wproj,wfc1,wfc2,tqkv,tproj,tfc1,tfc2);
  qkv_ln_kernel<<<dim3(392,3),256,0,stream>>>(x,ln1w,ln1b,tqkv,bqkv,qb,kb,vb);
  attn_kernel<<<dim3(49,16),256,0,stream>>>(qb,kb,vb,rpb,aout);
  mega_mlp_kernel<<<392,256,0,stream>>>(aout,x,tproj,bproj,ln2w,ln2b,
                                        tfc1,bfc1,tfc2,bfc2,(float*)d_out);
}

// Round 8
// 129.998 us; speedup vs baseline: 1.2155x; 1.0796x over previous
//
#include <hip/hip_runtime.h>

using bf16x8 = __attribute__((ext_vector_type(8))) short;
using f32x4  = __attribute__((ext_vector_type(4))) float;
typedef unsigned short u16;
typedef __attribute__((ext_vector_type(8))) unsigned short u16x8;
typedef __attribute__((ext_vector_type(4))) unsigned short u16x4;

__device__ __forceinline__ u16 f2b(float f){
  unsigned int i=__float_as_uint(f);
  return (u16)((i + 0x7FFFu + ((i>>16)&1u))>>16);
}
__device__ __forceinline__ float b2f(u16 u){
  union{unsigned int i; float f;}v; v.i=((unsigned int)u)<<16; return v.f;
}
__device__ __forceinline__ void async16(const void* g, void* l){
  __builtin_amdgcn_global_load_lds((__attribute__((address_space(1))) void*)(g),
                                   (__attribute__((address_space(3))) void*)(l), 16, 0, 0);
}
__device__ __forceinline__ float gelu_tanh(float v){
  float u = v*(0.7978845608f + 0.0356774081f*v*v);
  float e = __expf(-2.0f*fabsf(u));
  float th = (1.0f-e)/(1.0f+e);
  th = (u<0.f)? -th : th;
  return 0.5f*v*(1.0f+th);
}

// ---------- prep: fp32 weights -> bf16, PRE-SWIZZLED into LDS image order ----------
// Image: per 128x128 chunk, flat u16 index = (c*128 + n)*8 + e
//   n = output col within chunk, c = k-octet (k = c*8+e)
// Staging then reads global i*16 -> LDS i*16: fully coalesced, conflict-free reads.
__global__ void prep_kernel(const float* __restrict__ wqkv, const float* __restrict__ wproj,
                            const float* __restrict__ wfc1, const float* __restrict__ wfc2,
                            u16* __restrict__ tqkv, u16* __restrict__ tproj,
                            u16* __restrict__ tfc1, u16* __restrict__ tfc2)
{
  int idx = blockIdx.x*256 + threadIdx.x;
  if (idx < 49152){
    int nc = idx>>14, r = idx&16383, i = r>>3, e = r&7, n = i&127, c = i>>7;
    tqkv[idx] = f2b(wqkv[(c*8+e)*384 + nc*128 + n]);
  } else if (idx < 65536){
    int r = idx-49152; int i=r>>3, e=r&7, n=i&127, c=i>>7;
    tproj[r] = f2b(wproj[(c*8+e)*128 + n]);
  } else if (idx < 131072){
    int t = idx-65536; int nc=t>>14, r=t&16383, i=r>>3, e=r&7, n=i&127, c=i>>7;
    tfc1[t] = f2b(wfc1[(c*8+e)*512 + nc*128 + n]);
  } else if (idx < 196608){
    int t = idx-131072; int nc=t>>14, r=t&16383, i=r>>3, e=r&7, n=i&127, c=i>>7;
    tfc2[t] = f2b(wfc2[(nc*128 + c*8 + e)*128 + n]);
  }
}

// aout layout: per 32-token tile, c-major chunks:
//   u16 index = ((tok>>5)*16 + (ch>>3))*256 + (tok&31)*8 + (ch&7)

// ---------- K2: LN1 + one QKV chunk GEMM. 32-token tile, grid (392, 3) ----------
__global__ __launch_bounds__(256)
void qkv_ln_kernel(const float* __restrict__ x,
                   const float* __restrict__ ln1w, const float* __restrict__ ln1b,
                   const u16* __restrict__ tqkv, const float* __restrict__ bqkv,
                   u16* __restrict__ qb, u16* __restrict__ kb, u16* __restrict__ vb)
{
  __shared__ __align__(16) char smem[40960];
  char* lA = smem;            // 32x128 bf16 c-major chunks (8 KB)
  char* lB = smem + 8192;     // 128x128 bf16 c-major chunks (32 KB)

  const int tid = threadIdx.x;
  const int lane = tid&63, wid = tid>>6;
  const int quad = lane>>4, lrow = lane&15;
  const int m0 = blockIdx.x*32;
  const int nc = blockIdx.y;
  const int wm = (wid&1)*16, wn = (wid>>1)*64;

  // ---- stage weight chunk (coalesced: global i*16 -> LDS i*16) ----
  #pragma unroll
  for (int kk=0;kk<8;kk++){
    int i = tid + kk*256;          // 2048 chunks
    async16(tqkv + (size_t)nc*16384 + i*8, lB + i*16);
  }

  // ---- LN1 in registers: thread = (row=tid>>3, g=tid&7), 16 channels ----
  {
    const int row = tid>>3, g = tid&7;
    float xv[16];
    const float4* xr = (const float4*)(x + (size_t)(m0+row)*128 + g*16);
    float s=0.f, sq=0.f;
    #pragma unroll
    for (int c4=0;c4<4;c4++){
      float4 t = xr[c4];
      xv[c4*4]=t.x; xv[c4*4+1]=t.y; xv[c4*4+2]=t.z; xv[c4*4+3]=t.w;
      s += t.x+t.y+t.z+t.w;
      sq += t.x*t.x+t.y*t.y+t.z*t.z+t.w*t.w;
    }
    s  += __shfl_xor(s,1);  s  += __shfl_xor(s,2);  s  += __shfl_xor(s,4);
    sq += __shfl_xor(sq,1); sq += __shfl_xor(sq,2); sq += __shfl_xor(sq,4);
    float mean = s*0.0078125f;
    float rstd = rsqrtf(sq*0.0078125f - mean*mean + 1e-5f);
    const float4* wr = (const float4*)(ln1w + g*16);
    const float4* br = (const float4*)(ln1b + g*16);
    u16 nv[16];
    #pragma unroll
    for (int c4=0;c4<4;c4++){
      float4 w4 = wr[c4], b4 = br[c4];
      nv[c4*4]   = f2b((xv[c4*4]  -mean)*rstd*w4.x + b4.x);
      nv[c4*4+1] = f2b((xv[c4*4+1]-mean)*rstd*w4.y + b4.y);
      nv[c4*4+2] = f2b((xv[c4*4+2]-mean)*rstd*w4.z + b4.z);
      nv[c4*4+3] = f2b((xv[c4*4+3]-mean)*rstd*w4.w + b4.w);
    }
    #pragma unroll
    for (int cc=0;cc<2;cc++){
      u16x8 pk;
      #pragma unroll
      for (int e=0;e<8;e++) pk[e] = nv[cc*8+e];
      *(u16x8*)(lA + (((g*2+cc)*32 + row)<<4)) = pk;
    }
  }
  __syncthreads();

  // ---- MFMA: wave = 16 rows x 64 cols ----
  f32x4 acc[4] = {};
  #pragma unroll
  for (int ks=0;ks<4;ks++){
    bf16x8 af = ((const bf16x8*)lA)[(ks*4+quad)*32 + wm + lrow];
    #pragma unroll
    for (int j=0;j<4;j++){
      bf16x8 bfr = ((const bf16x8*)lB)[(ks*4+quad)*128 + wn + j*16 + lrow];
      acc[j] = __builtin_amdgcn_mfma_f32_16x16x32_bf16(af, bfr, acc[j], 0,0,0);
    }
  }

  const float scale = 0.17677669529663687f;
  u16* dst = (nc==0)? qb : ((nc==1)? kb : vb);
  #pragma unroll
  for (int j=0;j<4;j++){
    int col = wn + j*16 + lrow;
    float bia = bqkv[nc*128 + col];
    #pragma unroll
    for (int r=0;r<4;r++){
      int row = m0 + wm + quad*4 + r;
      float val = acc[j][r] + bia;
      if (nc==0) val *= scale;
      dst[(size_t)row*128 + col] = f2b(val);
    }
  }
}

// ---------- K3: MFMA neighborhood attention ----------
#define KT_S 40
#define VT_S 232
#define P_S  152
__global__ __launch_bounds__(256)
void attn_kernel(const u16* __restrict__ qb, const u16* __restrict__ kb,
                 const u16* __restrict__ vb, const float* __restrict__ rpb,
                 u16* __restrict__ aout)
{
  __shared__ __align__(16) char smem[50192];
  u16*  kt   = (u16*)smem;
  u16*  vt   = (u16*)(smem + 15680);
  u16*  Pm   = (u16*)(smem + 30528);
  float* srpb= (float*)(smem + 49984);

  const int tid = threadIdx.x;
  const int tile = blockIdx.x, bh = blockIdx.y;
  const int b = bh>>2, h = bh&3;
  const int ty = (tile/7)*8, tx = (tile%7)*8;
  const int lane = tid&63, wid = tid>>6;
  const int quad = lane>>4, lrow = lane&15;

  #pragma unroll
  for (int kk=0;kk<4;kk++){
    int i = tid + kk*256;
    if (i < 784){
      int pos = i>>2, oct = i&3;
      int hy = pos/14, hx = pos - hy*14;
      int gy = ty + hy - 3, gx = tx + hx - 3;
      u16x8 kv = {0,0,0,0,0,0,0,0};
      if (gy>=0 && gy<56 && gx>=0 && gx<56)
        kv = *(const u16x8*)(kb + ((size_t)(b*3136 + gy*56 + gx)*128 + h*32 + oct*8));
      *(u16x8*)(kt + pos*KT_S + oct*8) = kv;
    }
  }
  #pragma unroll
  for (int kk=0;kk<4;kk++){
    int i = tid + kk*256;
    if (i < 896){
      int pos = i>>2, oct = i&3;
      u16x8 vv = {0,0,0,0,0,0,0,0};
      if (pos < 196){
        int hy = pos/14, hx = pos - hy*14;
        int gy = ty + hy - 3, gx = tx + hx - 3;
        if (gy>=0 && gy<56 && gx>=0 && gx<56)
          vv = *(const u16x8*)(vb + ((size_t)(b*3136 + gy*56 + gx)*128 + h*32 + oct*8));
      }
      #pragma unroll
      for (int j=0;j<8;j++) vt[(oct*8+j)*VT_S + pos] = vv[j];
    }
  }
  if (tid < 49) srpb[tid] = rpb[h*49 + tid];
  __syncthreads();

  const int pxq = wid*16 + lrow;
  const int tokq = b*3136 + (ty + (pxq>>3))*56 + tx + (pxq&7);
  bf16x8 qf = *(const bf16x8*)(qb + (size_t)tokq*128 + h*32 + quad*8);

  f32x4 sc[7];
  const f32x4 zf = {0.f,0.f,0.f,0.f};
  #pragma unroll
  for (int cg=0;cg<7;cg++){
    int pos = wid*28 + cg*16 + lrow;
    bf16x8 kf = *(const bf16x8*)(kt + pos*KT_S + quad*8);
    sc[cg] = __builtin_amdgcn_mfma_f32_16x16x32_bf16(qf, kf, zf, 0,0,0);
  }

  const int lyq = quad>>1;
  #pragma unroll
  for (int cg=0;cg<7;cg++){
    int np = cg*16 + lrow;
    int nh = np/14, hx = np - nh*14;
    int dy = nh - lyq;
    #pragma unroll
    for (int r=0;r<4;r++){
      int lx = (quad*4+r)&7;
      int dx = hx - lx;
      bool in = ((unsigned)dy<7u) && ((unsigned)dx<7u);
      float bias = srpb[in ? (dy*7+dx) : 0];
      sc[cg][r] = in ? (sc[cg][r] + bias) : -1e30f;
    }
  }
  float inv[4];
  #pragma unroll
  for (int r=0;r<4;r++){
    float m = sc[0][r];
    #pragma unroll
    for (int cg=1;cg<7;cg++) m = fmaxf(m, sc[cg][r]);
    m = fmaxf(m, __shfl_xor(m,1)); m = fmaxf(m, __shfl_xor(m,2));
    m = fmaxf(m, __shfl_xor(m,4)); m = fmaxf(m, __shfl_xor(m,8));
    float l = 0.f;
    #pragma unroll
    for (int cg=0;cg<7;cg++){ float p = __expf(sc[cg][r]-m); sc[cg][r]=p; l+=p; }
    l += __shfl_xor(l,1); l += __shfl_xor(l,2);
    l += __shfl_xor(l,4); l += __shfl_xor(l,8);
    inv[r]=1.f/l;
  }

  u16* Pw = Pm + wid*16*P_S;
  #pragma unroll
  for (int cg=0;cg<7;cg++){
    int np = cg*16 + lrow;
    #pragma unroll
    for (int r=0;r<4;r++)
      Pw[(quad*4+r)*P_S + np] = f2b(sc[cg][r]);
  }
  { int zr = lane>>2, seg = lane&3;
    u16x4 z4 = {0,0,0,0};
    *(u16x4*)(Pw + zr*P_S + 112 + seg*4) = z4; }
  __syncthreads();

  f32x4 oacc[2] = {zf, zf};
  #pragma unroll
  for (int ks=0;ks<4;ks++){
    bf16x8 pf = *(const bf16x8*)(Pw + lrow*P_S + ks*32 + quad*8);
    #pragma unroll
    for (int cg2=0;cg2<2;cg2++){
      bf16x8 vf = *(const bf16x8*)(vt + (cg2*16+lrow)*VT_S + wid*28 + ks*32 + quad*8);
      oacc[cg2] = __builtin_amdgcn_mfma_f32_16x16x32_bf16(pf, vf, oacc[cg2], 0,0,0);
    }
  }
  #pragma unroll
  for (int r=0;r<4;r++){
    int px = wid*16 + quad*4 + r;
    int tok = b*3136 + (ty + (px>>3))*56 + tx + (px&7);
    #pragma unroll
    for (int cg2=0;cg2<2;cg2++){
      int ch = h*32 + cg2*16 + lrow;
      aout[(size_t)((tok>>5)*16 + (ch>>3))*256 + (tok&31)*8 + (ch&7)]
        = f2b(oacc[cg2][r]*inv[r]);
    }
  }
}

// ---------- K4: PROJ + residual + LN2 + FC1 + GELU + FC2 + residual ----------
__global__ __launch_bounds__(256)
void mega_mlp_kernel(const u16* __restrict__ aout, const float* __restrict__ x,
                     const u16* __restrict__ tproj, const float* __restrict__ bproj,
                     const float* __restrict__ ln2w, const float* __restrict__ ln2b,
                     const u16* __restrict__ tfc1, const float* __restrict__ bfc1,
                     const u16* __restrict__ tfc2, const float* __restrict__ bfc2,
                     float* __restrict__ out)
{
  __shared__ __align__(16) char smem[49664];
  char* lA  = smem;            // 8 KB: aout tile -> hid chunk
  char* lB  = smem + 8192;     // 32 KB: weight chunk staging
  char* xn2 = smem + 40960;    // 8 KB: LN2 output bf16 (c-major chunks)
  float* redS = (float*)(smem + 49152);  // 64 floats
  float* redQ = redS + 64;               // 64 floats

  const int tid = threadIdx.x;
  const int lane = tid&63, wid = tid>>6;
  const int quad = lane>>4, lrow = lane&15;
  const int m0 = blockIdx.x*32;
  const int wm = (wid&1)*16, wn = (wid>>1)*64;
  const int half = wid>>1;

  // ---- stage aout tile + tproj (both coalesced i*16 -> i*16) ----
  #pragma unroll
  for (int kk=0;kk<2;kk++){
    int i = tid + kk*256;            // 512 chunks
    async16(aout + (size_t)blockIdx.x*4096 + i*8, lA + i*16);
  }
  #pragma unroll
  for (int kk=0;kk<8;kk++){
    int i = tid + kk*256;            // 2048 chunks
    async16(tproj + (size_t)i*8, lB + i*16);
  }
  __syncthreads();

  // ---- proj MFMA (wave = 16 rows x 64 cols) ----
  f32x4 acc[4] = {};
  #pragma unroll
  for (int ks=0;ks<4;ks++){
    bf16x8 af = ((const bf16x8*)lA)[(ks*4+quad)*32 + wm + lrow];
    #pragma unroll
    for (int j=0;j<4;j++){
      bf16x8 bfr = ((const bf16x8*)lB)[(ks*4+quad)*128 + wn + j*16 + lrow];
      acc[j] = __builtin_amdgcn_mfma_f32_16x16x32_bf16(af, bfr, acc[j], 0,0,0);
    }
  }

  // ---- x1 = proj + bias + x (registers) + row-stat partials ----
  float x1v[4][4];
  float ps[4] = {}, pq[4] = {};
  #pragma unroll
  for (int j=0;j<4;j++){
    int col = wn + j*16 + lrow;
    float bia = bproj[col];
    #pragma unroll
    for (int r=0;r<4;r++){
      int row = m0 + wm + quad*4 + r;
      float val = acc[j][r] + bia + x[(size_t)row*128 + col];
      x1v[j][r] = val;
      ps[r] += val; pq[r] += val*val;
    }
  }
  #pragma unroll
  for (int r=0;r<4;r++){
    #pragma unroll
    for (int off=1; off<16; off<<=1){
      ps[r] += __shfl_xor(ps[r], off);
      pq[r] += __shfl_xor(pq[r], off);
    }
  }
  if (lrow==0){
    #pragma unroll
    for (int r=0;r<4;r++){
      int row = wm + quad*4 + r;
      redS[half*32 + row] = ps[r];
      redQ[half*32 + row] = pq[r];
    }
  }
  __syncthreads();

  // ---- LN2 -> xn2 (bf16, c-major chunks) ----
  {
    float w2[4], b2[4];
    #pragma unroll
    for (int j=0;j<4;j++){ int col = wn+j*16+lrow; w2[j]=ln2w[col]; b2[j]=ln2b[col]; }
    #pragma unroll
    for (int r=0;r<4;r++){
      int row = wm + quad*4 + r;
      float mean = (redS[row] + redS[32+row])*0.0078125f;
      float var  = (redQ[row] + redQ[32+row])*0.0078125f - mean*mean;
      float rstd = rsqrtf(var + 1e-5f);
      #pragma unroll
      for (int j=0;j<4;j++){
        int col = wn + j*16 + lrow;
        u16 hv = f2b((x1v[j][r]-mean)*rstd*w2[j] + b2[j]);
        ((u16*)xn2)[((col>>3)*32 + row)*8 + (col&7)] = hv;
      }
    }
  }
  __syncthreads();

  // ---- FC1(chunk) + GELU + FC2(chunk) accumulate ----
  f32x4 acc3[4] = {};
  for (int nc=0; nc<4; nc++){
    if (nc>0) __syncthreads();
    #pragma unroll
    for (int kk=0;kk<8;kk++){
      int i = tid + kk*256;
      async16(tfc1 + (size_t)nc*16384 + i*8, lB + i*16);
    }
    __syncthreads();

    f32x4 acc2[4] = {};
    #pragma unroll
    for (int ks=0;ks<4;ks++){
      bf16x8 af = ((const bf16x8*)xn2)[(ks*4+quad)*32 + wm + lrow];
      #pragma unroll
      for (int j=0;j<4;j++){
        bf16x8 bfr = ((const bf16x8*)lB)[(ks*4+quad)*128 + wn + j*16 + lrow];
        acc2[j] = __builtin_amdgcn_mfma_f32_16x16x32_bf16(af, bfr, acc2[j], 0,0,0);
      }
    }
    #pragma unroll
    for (int j=0;j<4;j++){
      int col = wn + j*16 + lrow;
      float bia = bfc1[nc*128 + col];
      #pragma unroll
      for (int r=0;r<4;r++){
        int row = wm + quad*4 + r;
        float g = gelu_tanh(acc2[j][r] + bia);
        ((u16*)lA)[((col>>3)*32 + row)*8 + (col&7)] = f2b(g);
      }
    }
    __syncthreads();
    #pragma unroll
    for (int kk=0;kk<8;kk++){
      int i = tid + kk*256;
      async16(tfc2 + (size_t)nc*16384 + i*8, lB + i*16);
    }
    __syncthreads();

    #pragma unroll
    for (int ks=0;ks<4;ks++){
      bf16x8 af = ((const bf16x8*)lA)[(ks*4+quad)*32 + wm + lrow];
      #pragma unroll
      for (int j=0;j<4;j++){
        bf16x8 bfr = ((const bf16x8*)lB)[(ks*4+quad)*128 + wn + j*16 + lrow];
        acc3[j] = __builtin_amdgcn_mfma_f32_16x16x32_bf16(af, bfr, acc3[j], 0,0,0);
      }
    }
  }

  // ---- epilogue: out = fc2 + bias + x1 ----
  #pragma unroll
  for (int j=0;j<4;j++){
    int col = wn + j*16 + lrow;
    float bia = bfc2[col];
    #pragma unroll
    for (int r=0;r<4;r++){
      int row = m0 + wm + quad*4 + r;
      out[(size_t)row*128 + col] = acc3[j][r] + bia + x1v[j][r];
    }
  }
}

extern "C" void kernel_launch(void* const* d_in, const int* in_sizes, int n_in,
                              void* d_out, int out_size, void* d_ws, size_t ws_size,
                              hipStream_t stream)
{
  const float* x     =(const float*)d_in[0];
  const float* ln1w  =(const float*)d_in[1];
  const float* ln1b  =(const float*)d_in[2];
  const float* wqkv  =(const float*)d_in[3];
  const float* bqkv  =(const float*)d_in[4];
  const float* rpb   =(const float*)d_in[5];
  const float* wproj =(const float*)d_in[6];
  const float* bproj =(const float*)d_in[7];
  const float* ln2w  =(const float*)d_in[8];
  const float* ln2b  =(const float*)d_in[9];
  const float* wfc1  =(const float*)d_in[10];
  const float* bfc1  =(const float*)d_in[11];
  const float* wfc2  =(const float*)d_in[12];
  const float* bfc2  =(const float*)d_in[13];

  char* ws=(char*)d_ws;
  size_t o=0;
  u16* tqkv =(u16*)(ws+o); o+=98304;
  u16* tproj=(u16*)(ws+o); o+=32768;
  u16* tfc1 =(u16*)(ws+o); o+=131072;
  u16* tfc2 =(u16*)(ws+o); o+=131072;
  u16* aout =(u16*)(ws+o); o+=3211264;
  u16* qb   =(u16*)(ws+o); o+=3211264;
  u16* kb   =(u16*)(ws+o); o+=3211264;
  u16* vb   =(u16*)(ws+o); o+=3211264;

  prep_kernel<<<768,256,0,stream>>>(wqkv,wproj,wfc1,wfc2,tqkv,tproj,tfc1,tfc2);
  qkv_ln_kernel<<<dim3(392,3),256,0,stream>>>(x,ln1w,ln1b,tqkv,bqkv,qb,kb,vb);
  attn_kernel<<<dim3(49,16),256,0,stream>>>(qb,kb,vb,rpb,aout);
  mega_mlp_kernel<<<392,256,0,stream>>>(aout,x,tproj,bproj,ln2w,ln2b,
                                        tfc1,bfc1,tfc2,bfc2,(float*)d_out);
}